// Round 3
// baseline (476.178 us; speedup 1.0000x reference)
//
#include <hip/hip_runtime.h>
#include <stdint.h>

#define N_ATOMS 500000
#define N_MOLS  25000
#define HID     300
#define BA      64        // atoms per block
#define WS_ELE  102400    // elements per repacked W matrix (20*10*64*8)
#define NCH     19        // 16-wide K chunks covering k<304 (rest is all pad)

// LDS per-buffer layout (bytes)
#define A_OFF   0
#define AROW    40        // 20 bf16 per atom row (16 used + pad for banks)
#define B_OFF   2560      // A region = 64*40 = 2560
#define BUFSZ   23040     // 2560 + 20*1024 (10 W-chunks + 10 V-chunks)

typedef __attribute__((ext_vector_type(8)))  short          short8v;
typedef __attribute__((ext_vector_type(16))) float          f32x16;

static __device__ __forceinline__ unsigned short f2bf(float f) {
  unsigned int u = __float_as_uint(f);
  u += 0x7fffu + ((u >> 16) & 1u);   // round-to-nearest-even
  return (unsigned short)(u >> 16);
}

// async global->LDS, 16B per lane; lds base wave-uniform.
static __device__ __forceinline__ void stage16(const char* gsrc, char* ldst, int ln) {
  __builtin_amdgcn_global_load_lds(
      (const __attribute__((address_space(1))) void*)(gsrc + ln * 16),
      (__attribute__((address_space(3))) void*)ldst, 16, 0, 0);
}

// ---------------------------------------------------------------------------
// Prep: repack W1/V1 into B-fragment order [kc16:20][nt:10][lane:64][j:8]
// (k = kc16*16 + (lane>>5)*8 + j, n = nt*32 + (lane&31)), pad biases/readout
// vectors to 320, zero the segment-sum accumulators.
// ---------------------------------------------------------------------------
__global__ void prep_kernel(
    const float* __restrict__ W1, const float* __restrict__ V1,
    const float* __restrict__ b1, const float* __restrict__ vb1,
    const float* __restrict__ W2, const float* __restrict__ V2,
    unsigned short* __restrict__ W1s, unsigned short* __restrict__ V1s,
    float* __restrict__ b1p, float* __restrict__ vb1p,
    float* __restrict__ W2p, float* __restrict__ V2p,
    float* __restrict__ sums)
{
  const int t = blockIdx.x * 256 + threadIdx.x;
  if (t < 2 * WS_ELE) {
    const float* src = (t < WS_ELE) ? W1 : V1;
    unsigned short* dst = (t < WS_ELE) ? W1s : V1s;
    const int i    = (t < WS_ELE) ? t : t - WS_ELE;
    const int j    = i & 7;
    const int lane = (i >> 3) & 63;
    const int nt   = (i >> 9) % 10;
    const int kc16 = i / 5120;
    const int k = kc16 * 16 + (lane >> 5) * 8 + j;
    const int n = nt * 32 + (lane & 31);
    const float v = (k < HID && n < HID) ? src[k * HID + n] : 0.f;
    dst[i] = f2bf(v);
  } else if (t < 2 * WS_ELE + 1280) {
    const int i = t - 2 * WS_ELE;
    const int which = i / 320;
    const int e = i - which * 320;
    const float* s = (which == 0) ? b1 : (which == 1) ? vb1 : (which == 2) ? W2 : V2;
    float*       d = (which == 0) ? b1p : (which == 1) ? vb1p : (which == 2) ? W2p : V2p;
    d[e] = (e < HID) ? s[e] : 0.f;
  } else if (t < 2 * WS_ELE + 1280 + 2 * N_MOLS) {
    sums[t - (2 * WS_ELE + 1280)] = 0.f;
  }
}

// ---------------------------------------------------------------------------
// Fused FFN x2. Block = 64 atoms, 8 waves = 2 row-groups x 2 col-halves x
// {W,V}. Each wave: 32 atoms x 160 cols, ONE matrix -> acc 5 x f32x16 = 80
// VGPR. A staged in LDS as bf16 (shared by W- and V-waves), B double-buffered
// via global_load_lds; chunk K=16, one barrier per chunk. launch_bounds
// caps VGPR<=128 so 2 blocks (16 waves) fit per CU alongside 2x23KB LDS.
// ---------------------------------------------------------------------------
__global__ __launch_bounds__(512, 4) void fused_ffn(
    const float* __restrict__ hidden,
    const unsigned short* __restrict__ W1s, const unsigned short* __restrict__ V1s,
    const float* __restrict__ b1p, const float* __restrict__ vb1p,
    const float* __restrict__ W2p, const float* __restrict__ V2p,
    const float* __restrict__ b2, const float* __restrict__ vb2,
    float* __restrict__ outA, float* __restrict__ outW)
{
  __shared__ char lds[2 * BUFSZ];   // 46,080 B
  __shared__ float sOutA[BA];
  __shared__ float sOutW[BA];

  const int tid = (int)threadIdx.x;
  const int ln  = tid & 63;
  const int wv  = tid >> 6;
  const int mtx = wv & 1;          // 0 = W-pass, 1 = V-pass
  const int wn  = (wv >> 1) & 1;   // col half (160 cols)
  const int wm  = wv >> 2;         // row group (32 atoms)
  const int l31 = ln & 31;
  const int lh  = ln >> 5;
  const long base = (long)blockIdx.x * BA;

  // A-staging role: thread t stages atom sa, k-pair skk of each chunk
  const int sa  = tid >> 3;
  const int skk = (tid & 7) * 2;
  const long satom = base + sa;
  const bool aok = satom < N_ATOMS;
  const float* srow = hidden + (aok ? satom : 0) * (long)HID;

  const float bias2A = b2[0];
  const float bias2W = vb2[0];

  f32x16 acc[5] = {};

  // ---- prologue: A(0) + B(0) into buf 0 ----
  {
    const int k = skk;             // chunk 0
    float2 av = make_float2(0.f, 0.f);
    if (aok) av = *reinterpret_cast<const float2*>(srow + k);
    // B chunk 0: 20KB = 20 x 1KB wave-chunks
    #pragma unroll
    for (int r = 0; r < 3; ++r) {
      const int c = r * 8 + wv;
      if (c < 20) {
        const char* src = (c < 10) ? ((const char*)W1s + c * 1024)
                                   : ((const char*)V1s + (c - 10) * 1024);
        stage16(src, lds + B_OFF + c * 1024, ln);
      }
    }
    ushort2 bv; bv.x = f2bf(av.x); bv.y = f2bf(av.y);
    *reinterpret_cast<ushort2*>(lds + A_OFF + sa * AROW + skk * 2) = bv;
  }
  __syncthreads();

  // ---- main loop over 19 chunks of K=16 ----
  for (int c = 0; c < NCH; ++c) {
    const int cur = c & 1;
    const char* cbuf = lds + cur * BUFSZ;
    char*       nbuf = lds + (cur ^ 1) * BUFSZ;

    float2 av = make_float2(0.f, 0.f);
    if (c < NCH - 1) {
      // A-reg loads FIRST (so their waitcnt doesn't drain the B stage)
      const int k = (c + 1) * 16 + skk;
      if (aok && k < HID) av = *reinterpret_cast<const float2*>(srow + k);
      // B stage for chunk c+1 into the other buffer
      const char* wsrc = (const char*)W1s + (c + 1) * 10240;
      const char* vsrc = (const char*)V1s + (c + 1) * 10240;
      #pragma unroll
      for (int r = 0; r < 3; ++r) {
        const int cc = r * 8 + wv;
        if (cc < 20) {
          const char* src = (cc < 10) ? (wsrc + cc * 1024) : (vsrc + (cc - 10) * 1024);
          stage16(src, nbuf + B_OFF + cc * 1024, ln);
        }
      }
    }

    // compute chunk c from cbuf
    const short8v af = *reinterpret_cast<const short8v*>(
        cbuf + A_OFF + (wm * 32 + l31) * AROW + lh * 16);
    const char* bbase = cbuf + B_OFF + mtx * 10240;
    #pragma unroll
    for (int nt = 0; nt < 5; ++nt) {
      const short8v bf = *reinterpret_cast<const short8v*>(
          bbase + (wn * 5 + nt) * 1024 + ln * 16);
      acc[nt] = __builtin_amdgcn_mfma_f32_32x32x16_bf16(af, bf, acc[nt], 0, 0, 0);
    }

    if (c < NCH - 1) {
      ushort2 bv; bv.x = f2bf(av.x); bv.y = f2bf(av.y);
      *reinterpret_cast<ushort2*>(nbuf + A_OFF + sa * AROW + skk * 2) = bv;
    }
    __syncthreads();
  }

  // ---- epilogue: out[atom] = sum_n relu(X+b1)*W2 + b2 ----
  float bv[5], w2[5];
  const float* bbv = mtx ? vb1p : b1p;
  const float* ww2 = mtx ? V2p  : W2p;
  #pragma unroll
  for (int nt = 0; nt < 5; ++nt) {
    const int cix = wn * 160 + nt * 32 + l31;
    bv[nt] = bbv[cix];
    w2[nt] = ww2[cix];
  }
  if (tid < BA) { sOutA[tid] = 0.f; sOutW[tid] = 0.f; }
  __syncthreads();

  float* sOut = mtx ? sOutW : sOutA;
  #pragma unroll
  for (int r = 0; r < 16; ++r) {
    float s = 0.f;
    #pragma unroll
    for (int nt = 0; nt < 5; ++nt) {
      float x = fmaxf(acc[nt][r] + bv[nt], 0.f);
      s = fmaf(x, w2[nt], s);
    }
    s += __shfl_xor(s, 1);
    s += __shfl_xor(s, 2);
    s += __shfl_xor(s, 4);
    s += __shfl_xor(s, 8);
    s += __shfl_xor(s, 16);
    if (l31 == 0) {
      const int row = (r & 3) + 8 * (r >> 2) + 4 * lh;
      atomicAdd(&sOut[wm * 32 + row], s);
    }
  }
  __syncthreads();
  if (tid < BA) {
    const long atom = base + tid;
    if (atom < N_ATOMS) {
      outA[atom] = sOutA[tid] + bias2A;
      outW[atom] = sOutW[tid] + bias2W;
    }
  }
}

// ---------------------------------------------------------------------------
// Segment sums: sorted seg_ids, run-compress 8 atoms/thread before atomics.
// ---------------------------------------------------------------------------
__global__ void segsum_kernel(
    const float* __restrict__ outA, const float* __restrict__ outW,
    const int* __restrict__ seg,
    float* __restrict__ sum_o, float* __restrict__ sum_w)
{
  const long i0 = ((long)blockIdx.x * 256 + threadIdx.x) * 8;
  if (i0 >= N_ATOMS) return;
  const int4   s0 = *reinterpret_cast<const int4*>(seg + i0);
  const int4   s1 = *reinterpret_cast<const int4*>(seg + i0 + 4);
  const float4 o0 = *reinterpret_cast<const float4*>(outA + i0);
  const float4 o1 = *reinterpret_cast<const float4*>(outA + i0 + 4);
  const float4 w0 = *reinterpret_cast<const float4*>(outW + i0);
  const float4 w1 = *reinterpret_cast<const float4*>(outW + i0 + 4);
  const int   ss[8] = {s0.x, s0.y, s0.z, s0.w, s1.x, s1.y, s1.z, s1.w};
  const float oo[8] = {o0.x, o0.y, o0.z, o0.w, o1.x, o1.y, o1.z, o1.w};
  const float ww[8] = {w0.x, w0.y, w0.z, w0.w, w1.x, w1.y, w1.z, w1.w};
  int cur = ss[0];
  float ao = 0.f, aw = 0.f;
  #pragma unroll
  for (int j = 0; j < 8; ++j) {
    if (ss[j] != cur) {
      atomicAdd(&sum_o[cur], ao);
      atomicAdd(&sum_w[cur], aw);
      cur = ss[j]; ao = 0.f; aw = 0.f;
    }
    ao += oo[j]; aw += ww[j];
  }
  atomicAdd(&sum_o[cur], ao);
  atomicAdd(&sum_w[cur], aw);
}

// ---------------------------------------------------------------------------
// Final: out = output + weights * (0 - sum_o[seg]) / sum_w'[seg]
// ---------------------------------------------------------------------------
__global__ void final_kernel(
    const float* __restrict__ outA, const float* __restrict__ outW,
    const int* __restrict__ seg,
    const float* __restrict__ sum_o, const float* __restrict__ sum_w,
    float* __restrict__ out)
{
  const long i0 = ((long)blockIdx.x * 256 + threadIdx.x) * 4;
  if (i0 >= N_ATOMS) return;
  const int4   s4 = *reinterpret_cast<const int4*>(seg + i0);
  const float4 o4 = *reinterpret_cast<const float4*>(outA + i0);
  const float4 w4 = *reinterpret_cast<const float4*>(outW + i0);
  const int   ss[4] = {s4.x, s4.y, s4.z, s4.w};
  const float oo[4] = {o4.x, o4.y, o4.z, o4.w};
  const float ww[4] = {w4.x, w4.y, w4.z, w4.w};
  float r[4];
  #pragma unroll
  for (int j = 0; j < 4; ++j) {
    const int s = ss[j];
    float sw = sum_w[s];
    sw = (sw == 0.f) ? 1.f : sw;
    const float corr = (0.f - sum_o[s]) / sw;
    r[j] = oo[j] + ww[j] * corr;
  }
  *reinterpret_cast<float4*>(out + i0) = make_float4(r[0], r[1], r[2], r[3]);
}

// ---------------------------------------------------------------------------
extern "C" void kernel_launch(void* const* d_in, const int* in_sizes, int n_in,
                              void* d_out, int out_size, void* d_ws, size_t ws_size,
                              hipStream_t stream)
{
  const float* hidden = (const float*)d_in[0];
  const int*   seg    = (const int*)d_in[1];
  const float* W1     = (const float*)d_in[2];
  const float* b1     = (const float*)d_in[3];
  const float* W2     = (const float*)d_in[4];
  const float* b2     = (const float*)d_in[5];
  const float* V1     = (const float*)d_in[6];
  const float* vb1    = (const float*)d_in[7];
  const float* V2     = (const float*)d_in[8];
  const float* vb2    = (const float*)d_in[9];

  char* ws = (char*)d_ws;
  float*          outA  = (float*)(ws + 0);          // 2,000,000 B
  float*          outW  = (float*)(ws + 2000000);    // 2,000,000 B
  float*          sum_o = (float*)(ws + 4000000);    //   100,000 B
  float*          sum_w = (float*)(ws + 4100000);    //   100,000 B
  unsigned short* W1s   = (unsigned short*)(ws + 4200000);  // 204,800 B
  unsigned short* V1s   = (unsigned short*)(ws + 4404800);  // 204,800 B
  float*          b1p   = (float*)(ws + 4609600);    // 1,280 B
  float*          vb1p  = (float*)(ws + 4610880);
  float*          W2p   = (float*)(ws + 4612160);
  float*          V2p   = (float*)(ws + 4613440);

  prep_kernel<<<1001, 256, 0, stream>>>(W1, V1, b1, vb1, W2, V2,
                                        W1s, V1s, b1p, vb1p, W2p, V2p, sum_o);

  const int nblk = (N_ATOMS + BA - 1) / BA;   // 7813
  fused_ffn<<<nblk, 512, 0, stream>>>(hidden, W1s, V1s, b1p, vb1p, W2p, V2p,
                                      b2, vb2, outA, outW);

  segsum_kernel<<<(N_ATOMS / 8 + 255) / 256, 256, 0, stream>>>(outA, outW, seg,
                                                               sum_o, sum_w);

  final_kernel<<<(N_ATOMS / 4 + 255) / 256, 256, 0, stream>>>(outA, outW, seg,
                                                              sum_o, sum_w,
                                                              (float*)d_out);
}